// Round 8
// baseline (440.781 us; speedup 1.0000x reference)
//
#include <hip/hip_runtime.h>
#include <math.h>

// GAT predictor: B=64, N=512, ATOM=34, GAT=128, HID=256, 3 layers + out.
// Round-8: barrier-free streaming MFMA kernels (A-fragments read directly from
// global; P/multi/x all stored in fragment-ready bf16 hi/lo layouts), 3
// independent GAT heads batched per dispatch, XCD-aware swizzle in agg.
// ws (256 MiB avail, ~219 MB used):
//   whtH3[3][64][128][512] | whtL3 | multiH[32768][384] | multiL | xH | xL |
//   WoT/WcT | src/dst[4][32768] | Pg3[3][32768][512]

#define ALPHA 0.2f
#define NEG_INF -9e15f

typedef __attribute__((ext_vector_type(8))) short s16x8;   // 8 bf16 (4 VGPRs)
typedef __attribute__((ext_vector_type(4))) float f32x4;
#define MFMA __builtin_amdgcn_mfma_f32_16x16x32_bf16

__device__ __forceinline__ ushort bf16_rne(float f) {
  union { float f; unsigned u; } v; v.f = f;
  unsigned r = v.u + 0x7FFFu + ((v.u >> 16) & 1u);
  return (ushort)(r >> 16);
}
__device__ __forceinline__ float bf16_tof(ushort h) {
  union { unsigned u; float f; } v; v.u = ((unsigned)h) << 16;
  return v.f;
}
__device__ __forceinline__ void split_store4(
    ushort* __restrict__ ph, ushort* __restrict__ pl,
    float v0, float v1, float v2, float v3) {
  ushort h0 = bf16_rne(v0), h1 = bf16_rne(v1), h2 = bf16_rne(v2), h3 = bf16_rne(v3);
  *(ushort4*)ph = make_ushort4(h0, h1, h2, h3);
  *(ushort4*)pl = make_ushort4(bf16_rne(v0 - bf16_tof(h0)), bf16_rne(v1 - bf16_tof(h1)),
                               bf16_rne(v2 - bf16_tof(h2)), bf16_rne(v3 - bf16_tof(h3)));
}
__device__ __forceinline__ void split_store1(
    ushort* __restrict__ ph, ushort* __restrict__ pl, float v) {
  ushort h = bf16_rne(v);
  *ph = h;
  *pl = bf16_rne(v - bf16_tof(h));
}

// ---- pack adj>0 into bitmask [32768][16] uint (parked in d_out head). ----
__global__ __launch_bounds__(256) void maskprep(
    const int* __restrict__ adj, unsigned* __restrict__ mask)
{
  const int gid = blockIdx.x * 256 + threadIdx.x;
  const int4* __restrict__ p = (const int4*)(adj + (long)gid * 32);
  unsigned m = 0;
#pragma unroll
  for (int k = 0; k < 8; k++) {
    const int4 v = p[k];
    m |= (v.x > 0 ? 1u : 0u) << (4 * k);
    m |= (v.y > 0 ? 1u : 0u) << (4 * k + 1);
    m |= (v.z > 0 ? 1u : 0u) << (4 * k + 2);
    m |= (v.w > 0 ? 1u : 0u) << (4 * k + 3);
  }
  mask[gid] = m;
}

// ---- transpose + hi/lo split weights: W[K,N] fp32 -> TH/TL[N][K]. ----
__global__ __launch_bounds__(256) void wt_prep(
    const float* __restrict__ W, ushort* __restrict__ TH, ushort* __restrict__ TL,
    const int Kd, const int Nd)
{
  const int idx = blockIdx.x * 256 + threadIdx.x;
  if (idx >= Kd * Nd) return;
  const int k = idx / Nd, n = idx % Nd;
  split_store1(&TH[(long)n * Kd + k], &TL[(long)n * Kd + k], W[idx]);
}

// ---- K1: Wh_l = compound @ W_l for all 3 layers -> whT bf16 hi/lo + src/dst.
// grid (1024, 3), blockIdx.y = layer. fp32 VALU (K=34, tiny). ----
__global__ __launch_bounds__(256) void wh_all(
    const float* __restrict__ A, const float* __restrict__ Wst,
    const float* __restrict__ avecB,
    ushort* __restrict__ whtH3, ushort* __restrict__ whtL3,
    float* __restrict__ srcB, float* __restrict__ dstB)
{
  __shared__ float AsT[34][36];
  __shared__ float Ws[34][128];
  const int t = threadIdx.x;
  const int l = blockIdx.y;
  const long row0 = (long)blockIdx.x * 32;
  const float* __restrict__ W = Wst + l * 4352;
  const float* __restrict__ avec = avecB + l * 256;
  ushort* __restrict__ whtH = whtH3 + (long)l * 4194304;
  ushort* __restrict__ whtL = whtL3 + (long)l * 4194304;
  float* __restrict__ src = srcB + l * 32768;
  float* __restrict__ dst = dstB + l * 32768;
  const int cg = t & 31, rg = t >> 5;
  {
    const int r = t >> 3, l8 = t & 7;
#pragma unroll
    for (int q = 0; q < 5; q++) {
      int k = l8 + q * 8;
      if (k < 34) AsT[k][r] = A[(row0 + r) * 34 + k];
    }
  }
  {
    int idx = t;
#pragma unroll
    for (int i = 0; i < 17; i++, idx += 256)
      Ws[idx >> 7][idx & 127] = W[idx];
  }
  __syncthreads();

  float acc[4][4];
#pragma unroll
  for (int r = 0; r < 4; r++)
#pragma unroll
    for (int c = 0; c < 4; c++) acc[r][c] = 0.f;
#pragma unroll 2
  for (int k = 0; k < 34; k++) {
    const float4 wv = *(const float4*)&Ws[k][cg * 4];
    const float4 av = *(const float4*)&AsT[k][rg * 4];
#define GFMA(r, a) \
    acc[r][0] += (a) * wv.x; acc[r][1] += (a) * wv.y; \
    acc[r][2] += (a) * wv.z; acc[r][3] += (a) * wv.w;
    GFMA(0, av.x) GFMA(1, av.y) GFMA(2, av.z) GFMA(3, av.w)
#undef GFMA
  }

  {
    const long tb = (row0 >> 9) * 65536;
    const int jloc = (int)(row0 & 511) + rg * 4;
#pragma unroll
    for (int cc = 0; cc < 4; cc++) {
      const long o = tb + (long)(cg * 4 + cc) * 512 + jloc;
      split_store4(&whtH[o], &whtL[o], acc[0][cc], acc[1][cc], acc[2][cc], acc[3][cc]);
    }
  }

  const float4 a1 = *(const float4*)&avec[cg * 4];
  const float4 a2 = *(const float4*)&avec[128 + cg * 4];
#pragma unroll
  for (int r = 0; r < 4; r++) {
    float s = acc[r][0]*a1.x + acc[r][1]*a1.y + acc[r][2]*a1.z + acc[r][3]*a1.w;
    float d = acc[r][0]*a2.x + acc[r][1]*a2.y + acc[r][2]*a2.z + acc[r][3]*a2.w;
#pragma unroll
    for (int w = 1; w < 32; w <<= 1) {
      s += __shfl_xor(s, w, 64);
      d += __shfl_xor(d, w, 64);
    }
    if (cg == 0) {
      src[row0 + rg * 4 + r] = s;
      dst[row0 + rg * 4 + r] = d;
    }
  }
}

// ---- K2a: scores -> normalized softmax P (bf16) to global. Bitmask adj.
// grid (32, 64, z), blockIdx.z = layer slot. ----
__global__ __launch_bounds__(256) void scores_kernel(
    const unsigned* __restrict__ mask,
    const float* __restrict__ srcB, const float* __restrict__ dstB,
    ushort* __restrict__ PgB)
{
  const int t = threadIdx.x;
  const int l = blockIdx.z;
  const long base = (long)blockIdx.y * 512;
  const int i0 = blockIdx.x * 16;
  const int r = t >> 4, l16 = t & 15;
  const long i = base + i0 + r;
  const float si = srcB[l * 32768 + i];
  const unsigned* __restrict__ mrow = mask + i * 16;
  const float* __restrict__ drow = dstB + l * 32768 + base;
  const int sh = (l16 & 7) * 4;
  float4 sv[8];
  float m = -INFINITY;
#pragma unroll
  for (int jj = 0; jj < 8; jj++) {
    const int j = jj * 64 + l16 * 4;
    const unsigned mw = mrow[2 * jj + (l16 >> 3)];
    const float4 dv = *(const float4*)&drow[j];
    float e0 = si + dv.x, e1 = si + dv.y, e2 = si + dv.z, e3 = si + dv.w;
    e0 = fmaxf(e0, ALPHA * e0); e1 = fmaxf(e1, ALPHA * e1);
    e2 = fmaxf(e2, ALPHA * e2); e3 = fmaxf(e3, ALPHA * e3);
    e0 = ((mw >> sh) & 1) ? e0 : NEG_INF;
    e1 = ((mw >> (sh + 1)) & 1) ? e1 : NEG_INF;
    e2 = ((mw >> (sh + 2)) & 1) ? e2 : NEG_INF;
    e3 = ((mw >> (sh + 3)) & 1) ? e3 : NEG_INF;
    sv[jj] = make_float4(e0, e1, e2, e3);
    m = fmaxf(m, fmaxf(fmaxf(e0, e1), fmaxf(e2, e3)));
  }
#pragma unroll
  for (int w = 1; w < 16; w <<= 1) m = fmaxf(m, __shfl_xor(m, w, 16));
  float sum = 0.f;
#pragma unroll
  for (int jj = 0; jj < 8; jj++) {
    float p0 = __expf(sv[jj].x - m), p1 = __expf(sv[jj].y - m);
    float p2 = __expf(sv[jj].z - m), p3 = __expf(sv[jj].w - m);
    sv[jj] = make_float4(p0, p1, p2, p3);
    sum += p0 + p1 + p2 + p3;
  }
#pragma unroll
  for (int w = 1; w < 16; w <<= 1) sum += __shfl_xor(sum, w, 16);
  const float inv = 1.f / sum;
  ushort* __restrict__ prow = PgB + (long)l * 16777216 + i * 512;
#pragma unroll
  for (int jj = 0; jj < 8; jj++) {
    const int j = jj * 64 + l16 * 4;
    *(ushort4*)&prow[j] = make_ushort4(
        bf16_rne(sv[jj].x * inv), bf16_rne(sv[jj].y * inv),
        bf16_rne(sv[jj].z * inv), bf16_rne(sv[jj].w * inv));
  }
}

// ---- K2b: out = elu(P @ WhT^T), barrier-free zero-LDS MFMA stream.
// grid (16, 64, z). A-fragments read directly from Pg (global); output split
// to bf16 hi/lo. XCD swizzle: 16 i-blocks of a (batch,layer) share one XCD. ----
__global__ __launch_bounds__(256) void agg_kernel(
    const ushort* __restrict__ PgB,
    const ushort* __restrict__ whH, const ushort* __restrict__ whL,
    ushort* __restrict__ outH, ushort* __restrict__ outL,
    const int ostride, const int ocoff_step)
{
  const int t = threadIdx.x;
  const long nb = (long)gridDim.x * gridDim.y * gridDim.z;
  const long bi = blockIdx.x + (long)gridDim.x * (blockIdx.y + (long)gridDim.y * blockIdx.z);
  const int c = (int)(bi & 7);
  const long kk = bi >> 3;
  const long gperc = nb >> 7;                 // groups per XCD
  const long g = (long)c * gperc + (kk >> 4); // (layer,batch) group
  const int iblk = (int)(kk & 15);
  const int z = (int)(g >> 6);
  const int batch = (int)(g & 63);
  const long base = (long)batch * 512;
  const int i0 = iblk * 32;

  const ushort* __restrict__ Pgp = PgB + (long)z * 16777216 + (base + i0) * 512;
  const int wv = t >> 6, lane = t & 63;
  const int m16 = lane & 15, q = lane >> 4;
  const int n0 = wv * 32;
  const ushort* __restrict__ a0p = Pgp + (long)m16 * 512;
  const ushort* __restrict__ a1p = Pgp + (long)(m16 + 16) * 512;
  const long wb = (long)z * 4194304 + base * 128 + (long)(n0 + m16) * 512;
  const ushort* __restrict__ bH = whH + wb;
  const ushort* __restrict__ bL = whL + wb;

  f32x4 acc00 = {0,0,0,0}, acc01 = {0,0,0,0}, acc10 = {0,0,0,0}, acc11 = {0,0,0,0};
#pragma unroll 4
  for (int kb = 0; kb < 16; kb++) {
    const int k0 = kb * 32 + q * 8;
    const s16x8 a0 = *(const s16x8*)&a0p[k0];
    const s16x8 a1 = *(const s16x8*)&a1p[k0];
    const s16x8 b0H = *(const s16x8*)&bH[k0];
    const s16x8 b0L = *(const s16x8*)&bL[k0];
    const s16x8 b1H = *(const s16x8*)&bH[8192 + k0];
    const s16x8 b1L = *(const s16x8*)&bL[8192 + k0];
    acc00 = MFMA(a0, b0H, acc00, 0, 0, 0);
    acc01 = MFMA(a0, b1H, acc01, 0, 0, 0);
    acc10 = MFMA(a1, b0H, acc10, 0, 0, 0);
    acc11 = MFMA(a1, b1H, acc11, 0, 0, 0);
    acc00 = MFMA(a0, b0L, acc00, 0, 0, 0);
    acc01 = MFMA(a0, b1L, acc01, 0, 0, 0);
    acc10 = MFMA(a1, b0L, acc10, 0, 0, 0);
    acc11 = MFMA(a1, b1L, acc11, 0, 0, 0);
  }
  const int ocoff = z * ocoff_step;
#pragma unroll
  for (int reg = 0; reg < 4; reg++) {
    const int row = q * 4 + reg;
    float v00 = acc00[reg], v01 = acc01[reg], v10 = acc10[reg], v11 = acc11[reg];
    v00 = v00 > 0.f ? v00 : expm1f(v00);
    v01 = v01 > 0.f ? v01 : expm1f(v01);
    v10 = v10 > 0.f ? v10 : expm1f(v10);
    v11 = v11 > 0.f ? v11 : expm1f(v11);
    const long o0 = (base + i0 + row) * (long)ostride + ocoff + n0 + m16;
    const long o1 = (base + i0 + 16 + row) * (long)ostride + ocoff + n0 + m16;
    split_store1(&outH[o0],      &outL[o0],      v00);
    split_store1(&outH[o0 + 16], &outL[o0 + 16], v01);
    split_store1(&outH[o1],      &outL[o1],      v10);
    split_store1(&outH[o1 + 16], &outL[o1 + 16], v11);
  }
}

// ---- K3/K4: C = A @ BT^T, barrier-free (A bf16 hi/lo fragments from global).
// 3-term compensation. MODE 0: emit whT hi/lo + src/dst. MODE 1: +bias+leaky fp32. ----
template<int K, int MODE>
__global__ __launch_bounds__(256) void mfma_gemm2(
    const ushort* __restrict__ AH, const ushort* __restrict__ AL,
    const ushort* __restrict__ BTH, const ushort* __restrict__ BTL,
    const float* __restrict__ bias, float* __restrict__ outF,
    ushort* __restrict__ whtH, ushort* __restrict__ whtL,
    const float* __restrict__ avec, float* __restrict__ src, float* __restrict__ dst,
    const int ostride)
{
  __shared__ float sredS[4][32], sredD[4][32];
  const int t = threadIdx.x;
  const long row0 = (long)blockIdx.x * 32;
  const int ncoff = (MODE == 1) ? blockIdx.y * 128 : 0;
  const int wv = t >> 6, lane = t & 63;
  const int m16 = lane & 15, q = lane >> 4;
  const int n0 = wv * 32;
  const ushort* __restrict__ aH0 = AH + (row0 + m16) * (long)K;
  const ushort* __restrict__ aL0 = AL + (row0 + m16) * (long)K;
  const ushort* __restrict__ aH1 = AH + (row0 + 16 + m16) * (long)K;
  const ushort* __restrict__ aL1 = AL + (row0 + 16 + m16) * (long)K;
  const ushort* __restrict__ bh = BTH + (long)(ncoff + n0 + m16) * K;
  const ushort* __restrict__ bl = BTL + (long)(ncoff + n0 + m16) * K;

  f32x4 acc[2][2];
#pragma unroll
  for (int m = 0; m < 2; m++)
#pragma unroll
    for (int n = 0; n < 2; n++) acc[m][n] = (f32x4){0.f, 0.f, 0.f, 0.f};

#pragma unroll 4
  for (int kg = 0; kg < K; kg += 32) {
    const int kq = kg + q * 8;
    const s16x8 a0H = *(const s16x8*)&aH0[kq];
    const s16x8 a0L = *(const s16x8*)&aL0[kq];
    const s16x8 a1H = *(const s16x8*)&aH1[kq];
    const s16x8 a1L = *(const s16x8*)&aL1[kq];
    const s16x8 b0H = *(const s16x8*)&bh[kq];
    const s16x8 b0L = *(const s16x8*)&bl[kq];
    const s16x8 b1H = *(const s16x8*)&bh[16 * K + kq];
    const s16x8 b1L = *(const s16x8*)&bl[16 * K + kq];
    acc[0][0] = MFMA(a0H, b0H, acc[0][0], 0, 0, 0);
    acc[0][1] = MFMA(a0H, b1H, acc[0][1], 0, 0, 0);
    acc[1][0] = MFMA(a1H, b0H, acc[1][0], 0, 0, 0);
    acc[1][1] = MFMA(a1H, b1H, acc[1][1], 0, 0, 0);
    acc[0][0] = MFMA(a0L, b0H, acc[0][0], 0, 0, 0);
    acc[0][1] = MFMA(a0L, b1H, acc[0][1], 0, 0, 0);
    acc[1][0] = MFMA(a1L, b0H, acc[1][0], 0, 0, 0);
    acc[1][1] = MFMA(a1L, b1H, acc[1][1], 0, 0, 0);
    acc[0][0] = MFMA(a0H, b0L, acc[0][0], 0, 0, 0);
    acc[0][1] = MFMA(a0H, b1L, acc[0][1], 0, 0, 0);
    acc[1][0] = MFMA(a1H, b0L, acc[1][0], 0, 0, 0);
    acc[1][1] = MFMA(a1H, b1L, acc[1][1], 0, 0, 0);
  }

  if (MODE == 0) {
    const long b = row0 >> 9;
    const int iloc = (int)(row0 & 511);
#pragma unroll
    for (int m = 0; m < 2; m++)
#pragma unroll
      for (int n = 0; n < 2; n++) {
        const int cc = n0 + n * 16 + m16;
        const long o = b * 65536 + (long)cc * 512 + iloc + m * 16 + q * 4;
        const f32x4 v = acc[m][n];
        split_store4(&whtH[o], &whtL[o], v[0], v[1], v[2], v[3]);
      }
    const float a10 = avec[n0 + m16], a11 = avec[n0 + 16 + m16];
    const float a20 = avec[128 + n0 + m16], a21 = avec[128 + n0 + 16 + m16];
#pragma unroll
    for (int m = 0; m < 2; m++) {
#pragma unroll
      for (int reg = 0; reg < 4; reg++) {
        float s = acc[m][0][reg] * a10 + acc[m][1][reg] * a11;
        float d = acc[m][0][reg] * a20 + acc[m][1][reg] * a21;
#pragma unroll
        for (int w = 1; w < 16; w <<= 1) {
          s += __shfl_xor(s, w, 64);
          d += __shfl_xor(d, w, 64);
        }
        if (m16 == 0) {
          const int row = m * 16 + q * 4 + reg;
          sredS[wv][row] = s;
          sredD[wv][row] = d;
        }
      }
    }
    __syncthreads();
    if (t < 32) {
      src[row0 + t] = sredS[0][t] + sredS[1][t] + sredS[2][t] + sredS[3][t];
      dst[row0 + t] = sredD[0][t] + sredD[1][t] + sredD[2][t] + sredD[3][t];
    }
  } else {
#pragma unroll
    for (int m = 0; m < 2; m++)
#pragma unroll
      for (int n = 0; n < 2; n++) {
        const int cc = ncoff + n0 + n * 16 + m16;
        const float bv = bias[cc];
#pragma unroll
        for (int reg = 0; reg < 4; reg++) {
          float v = acc[m][n][reg] + bv;
          v = fmaxf(v, ALPHA * v);
          outF[(row0 + m * 16 + q * 4 + reg) * (long)ostride + cc] = v;
        }
      }
  }
}

extern "C" void kernel_launch(void* const* d_in, const int* in_sizes, int n_in,
                              void* d_out, int out_size, void* d_ws, size_t ws_size,
                              hipStream_t stream) {
  const float* compound = (const float*)d_in[0];
  const int*   adj      = (const int*)d_in[1];
  const float* W_stack  = (const float*)d_in[2];
  const float* a_stack  = (const float*)d_in[3];
  const float* W_out    = (const float*)d_in[4];
  const float* a_out    = (const float*)d_in[5];
  const float* Wc       = (const float*)d_in[6];
  const float* bc       = (const float*)d_in[7];
  float* out = (float*)d_out;

  ushort* us      = (ushort*)d_ws;
  ushort* whtH3   = us;                       // 3 * 4,194,304
  ushort* whtL3   = whtH3 + 12582912;
  ushort* multiH  = whtL3 + 12582912;         // 32768 * 384
  ushort* multiL  = multiH + 12582912;
  ushort* xH      = multiL + 12582912;        // 32768 * 128
  ushort* xL      = xH + 4194304;
  ushort* WoT_H   = xL + 4194304;             // 49152
  ushort* WoT_L   = WoT_H + 49152;
  ushort* WcT_H   = WoT_L + 49152;            // 32768
  ushort* WcT_L   = WcT_H + 32768;
  float*  src_all = (float*)(WcT_L + 32768);  // 4 * 32768
  float*  dst_all = src_all + 131072;
  ushort* Pg3     = (ushort*)(dst_all + 131072);  // 3 * 16,777,216 (~100 MB)
  unsigned* mask  = (unsigned*)d_out;         // 2.1 MB, dead until final GEMM

  maskprep<<<2048, 256, 0, stream>>>(adj, mask);
  wt_prep<<<192, 256, 0, stream>>>(W_out, WoT_H, WoT_L, 384, 128);
  wt_prep<<<128, 256, 0, stream>>>(Wc, WcT_H, WcT_L, 128, 256);

  // 3 independent GAT heads, batched per stage
  wh_all<<<dim3(1024, 3), 256, 0, stream>>>(
      compound, W_stack, a_stack, whtH3, whtL3, src_all, dst_all);
  scores_kernel<<<dim3(32, 64, 3), 256, 0, stream>>>(mask, src_all, dst_all, Pg3);
  agg_kernel<<<dim3(16, 64, 3), 256, 0, stream>>>(
      Pg3, whtH3, whtL3, multiH, multiL, 384, 128);

  // layer 4: whT = multi @ W_out (+ src/dst), then attention
  mfma_gemm2<384, 0><<<1024, 256, 0, stream>>>(
      multiH, multiL, WoT_H, WoT_L, nullptr, nullptr, whtH3, whtL3,
      a_out, src_all + 98304, dst_all + 98304, 0);
  scores_kernel<<<dim3(32, 64, 1), 256, 0, stream>>>(
      mask, src_all + 98304, dst_all + 98304, Pg3);
  agg_kernel<<<dim3(16, 64, 1), 256, 0, stream>>>(
      Pg3, whtH3, whtL3, xH, xL, 128, 0);

  // final: out = leaky(x @ Wc + bc)
  mfma_gemm2<128, 1><<<dim3(1024, 2), 256, 0, stream>>>(
      xH, xL, WcT_H, WcT_L, bc, out, nullptr, nullptr, nullptr, nullptr, nullptr, 256);
}